// Round 7
// baseline (713.205 us; speedup 1.0000x reference)
//
#include <hip/hip_runtime.h>
#include <hip/hip_bf16.h>

#define N_NODES 100000
#define N_EDGES 1600000
#define IN_DIM 128
#define HID 64

// ---------------- threefry2x32, key = (0, 42) ----------------
__device__ __forceinline__ unsigned rotl32(unsigned x, unsigned r) {
    return (x << r) | (x >> (32u - r));
}

__device__ __forceinline__ void threefry2x32_k42(unsigned x0, unsigned x1,
                                                 unsigned& o0, unsigned& o1) {
    const unsigned ks0 = 0u;
    const unsigned ks1 = 42u;
    const unsigned ks2 = 0u ^ 42u ^ 0x1BD11BDAu;
    x0 += ks0; x1 += ks1;
    x0 += x1; x1 = rotl32(x1, 13); x1 ^= x0;
    x0 += x1; x1 = rotl32(x1, 15); x1 ^= x0;
    x0 += x1; x1 = rotl32(x1, 26); x1 ^= x0;
    x0 += x1; x1 = rotl32(x1, 6);  x1 ^= x0;
    x0 += ks1; x1 += ks2 + 1u;
    x0 += x1; x1 = rotl32(x1, 17); x1 ^= x0;
    x0 += x1; x1 = rotl32(x1, 29); x1 ^= x0;
    x0 += x1; x1 = rotl32(x1, 16); x1 ^= x0;
    x0 += x1; x1 = rotl32(x1, 24); x1 ^= x0;
    x0 += ks2; x1 += ks0 + 2u;
    x0 += x1; x1 = rotl32(x1, 13); x1 ^= x0;
    x0 += x1; x1 = rotl32(x1, 15); x1 ^= x0;
    x0 += x1; x1 = rotl32(x1, 26); x1 ^= x0;
    x0 += x1; x1 = rotl32(x1, 6);  x1 ^= x0;
    x0 += ks0; x1 += ks1 + 3u;
    x0 += x1; x1 = rotl32(x1, 17); x1 ^= x0;
    x0 += x1; x1 = rotl32(x1, 29); x1 ^= x0;
    x0 += x1; x1 = rotl32(x1, 16); x1 ^= x0;
    x0 += x1; x1 = rotl32(x1, 24); x1 ^= x0;
    x0 += ks1; x1 += ks2 + 4u;
    x0 += x1; x1 = rotl32(x1, 13); x1 ^= x0;
    x0 += x1; x1 = rotl32(x1, 15); x1 ^= x0;
    x0 += x1; x1 = rotl32(x1, 26); x1 ^= x0;
    x0 += x1; x1 = rotl32(x1, 6);  x1 ^= x0;
    x0 += ks2; x1 += ks0 + 5u;
    o0 = x0; o1 = x1;
}

// ---------------- edge-index dtype detection (int64 vs int32) ----------------
__global__ void k_detect(const unsigned* __restrict__ ei_words, int* __restrict__ flag) {
    __shared__ unsigned red[256];
    int t = threadIdx.x;
    unsigned acc = 0;
    for (int i = t; i < 4096; i += 256) acc |= ei_words[2 * i + 1];
    red[t] = acc;
    __syncthreads();
    for (int s = 128; s; s >>= 1) {
        if (t < s) red[t] |= red[t + s];
        __syncthreads();
    }
    if (t == 0) *flag = (red[0] == 0u) ? 1 : 0;  // 1 => int64
}

__device__ __forceinline__ int edge_at(const int* __restrict__ e32,
                                       const long long* __restrict__ e64,
                                       int is64, int j) {
    return is64 ? (int)e64[j] : e32[j];
}

// ---------------- h = x @ W_conv  [100000,128]x[128,64] -> fp32 ----------------
__global__ __launch_bounds__(256) void k_gemm(const float* __restrict__ x,
                                              const float* __restrict__ W,
                                              float* __restrict__ h) {
    __shared__ float Wl[IN_DIM * HID];  // 32 KB
    __shared__ float xs[16][IN_DIM];    // 8 KB
    const int t = threadIdx.x;
    const float4* W4 = (const float4*)W;
    for (int i = t; i < IN_DIM * HID / 4; i += 256) ((float4*)Wl)[i] = W4[i];
    const int base = blockIdx.x * 16;
    const float4* x4 = (const float4*)(x + (size_t)base * IN_DIM);
    for (int i = t; i < 16 * IN_DIM / 4; i += 256) ((float4*)xs)[i] = x4[i];
    __syncthreads();
    const int d = t & 63, g = t >> 6;
    float a0 = 0.f, a1 = 0.f, a2 = 0.f, a3 = 0.f;
#pragma unroll 4
    for (int k = 0; k < IN_DIM; k++) {
        float w = Wl[k * HID + d];
        a0 += xs[g][k] * w;
        a1 += xs[g + 4][k] * w;
        a2 += xs[g + 8][k] * w;
        a3 += xs[g + 12][k] * w;
    }
    h[(size_t)(base + g) * HID + d] = a0;
    h[(size_t)(base + g + 4) * HID + d] = a1;
    h[(size_t)(base + g + 8) * HID + d] = a2;
    h[(size_t)(base + g + 12) * HID + d] = a3;
}

// ---------------- CSR build ----------------
__global__ void k_zero(int* __restrict__ cnt) {
    int i = blockIdx.x * 256 + threadIdx.x;
    if (i < N_NODES) cnt[i] = 0;
}

__global__ void k_hist(const int* __restrict__ e32, const long long* __restrict__ e64,
                       const int* __restrict__ flag, int* __restrict__ cnt) {
    int e = blockIdx.x * 256 + threadIdx.x;
    if (e < N_EDGES) {
        int c = edge_at(e32, e64, *flag, N_EDGES + e);
        atomicAdd(&cnt[c], 1);
    }
}

// single block, 1024 threads: exclusive scan of cnt -> row_start[100001],
// cursor copy, and dinv = rsqrt(cnt+1)
#define CHUNK 98  // 98*1024 = 100352 >= 100000
__global__ __launch_bounds__(1024) void k_scan(const int* __restrict__ cnt,
                                               int* __restrict__ row_start,
                                               int* __restrict__ cursor,
                                               float* __restrict__ dinv) {
    __shared__ int s[1024];
    const int t = threadIdx.x;
    const int lo = t * CHUNK;
    const int hi = min(lo + CHUNK, N_NODES);
    int psum = 0;
    for (int i = lo; i < hi; i++) psum += cnt[i];
    s[t] = psum;
    __syncthreads();
    for (int off = 1; off < 1024; off <<= 1) {
        int v = (t >= off) ? s[t - off] : 0;
        __syncthreads();
        s[t] += v;
        __syncthreads();
    }
    int run = s[t] - psum;  // exclusive base for this chunk
    for (int i = lo; i < hi; i++) {
        row_start[i] = run;
        cursor[i] = run;
        dinv[i] = rsqrtf((float)(cnt[i] + 1));
        run += cnt[i];
    }
    if (t == 1023) row_start[N_NODES] = s[1023];
}

__global__ void k_fill(const int* __restrict__ e32, const long long* __restrict__ e64,
                       const int* __restrict__ flag, int* __restrict__ cursor,
                       int* __restrict__ srcs) {
    int e = blockIdx.x * 256 + threadIdx.x;
    if (e >= N_EDGES) return;
    int f = *flag;
    int r = edge_at(e32, e64, f, e);
    int c = edge_at(e32, e64, f, N_EDGES + e);
    int pos = atomicAdd(&cursor[c], 1);
    srcs[pos] = r;
}

// ---------------- fused gather + self + bias/relu/dropout + [64->2] matvec ----------
__global__ __launch_bounds__(256) void k_aggr(const float* __restrict__ h,
                                              const int* __restrict__ row_start,
                                              const int* __restrict__ srcs,
                                              const float* __restrict__ dinv,
                                              const float* __restrict__ bconv,
                                              const float* __restrict__ Wlin,
                                              const float* __restrict__ blin,
                                              float* __restrict__ out) {
    const int c = blockIdx.x * 4 + (threadIdx.x >> 6);
    const int d = threadIdx.x & 63;
    const float dc = dinv[c];
    float acc = h[(size_t)c * HID + d] * dc;  // self-loop (dc factored once more at end)
    const int beg = row_start[c];
    const int end = row_start[c + 1];
    int j = beg;
    // unroll by 2 for independent outstanding loads
    for (; j + 1 < end; j += 2) {
        int r0 = srcs[j];
        int r1 = srcs[j + 1];
        float w0 = dinv[r0];
        float w1 = dinv[r1];
        float v0 = h[(size_t)r0 * HID + d];
        float v1 = h[(size_t)r1 * HID + d];
        acc += w0 * v0;
        acc += w1 * v1;
    }
    if (j < end) {
        int r = srcs[j];
        acc += dinv[r] * h[(size_t)r * HID + d];
    }
    float v = acc * dc + bconv[d];
    v = fmaxf(v, 0.f);
    // dropout: bits = o0^o1 of threefry((0,42),(0,i)), keep iff MSB==0
    unsigned i = (unsigned)(c * HID + d);
    unsigned o0, o1;
    threefry2x32_k42(0u, i, o0, o1);
    v = ((o0 ^ o1) & 0x80000000u) ? 0.f : v * 2.f;
    float a0 = v * Wlin[d * 2 + 0];
    float a1 = v * Wlin[d * 2 + 1];
#pragma unroll
    for (int off = 32; off; off >>= 1) {
        a0 += __shfl_down(a0, off);
        a1 += __shfl_down(a1, off);
    }
    if (d == 0) {
        out[(size_t)c * 2 + 0] = a0 + blin[0];
        out[(size_t)c * 2 + 1] = a1 + blin[1];
    }
}

extern "C" void kernel_launch(void* const* d_in, const int* in_sizes, int n_in,
                              void* d_out, int out_size, void* d_ws, size_t ws_size,
                              hipStream_t stream) {
    // Map inputs BY ELEMENT COUNT (all unique) — robust to positional order.
    const float* x  = (const float*)d_in[0];
    const void*  ei = d_in[1];
    const float* Wc = (const float*)d_in[2];
    const float* bc = (const float*)d_in[3];
    const float* Wl = (const float*)d_in[4];
    const float* bl = (const float*)d_in[5];
    for (int i = 0; i < n_in; i++) {
        switch (in_sizes[i]) {
            case N_NODES * IN_DIM:   x  = (const float*)d_in[i]; break;
            case 2 * N_EDGES:
            case 4 * N_EDGES:        ei = d_in[i]; break;
            case IN_DIM * HID:       Wc = (const float*)d_in[i]; break;
            case HID:                bc = (const float*)d_in[i]; break;
            case HID * 2:            Wl = (const float*)d_in[i]; break;
            case 2:                  bl = (const float*)d_in[i]; break;
            default: break;
        }
    }
    float* out = (float*)d_out;

    char* ws = (char*)d_ws;
    size_t off = 0;
    float* h         = (float*)(ws + off); off += (size_t)N_NODES * HID * 4;  // 25.6 MB
    int*   cnt       = (int*)(ws + off);   off += (size_t)N_NODES * 4;
    int*   row_start = (int*)(ws + off);   off += (size_t)(N_NODES + 4) * 4;
    int*   cursor    = (int*)(ws + off);   off += (size_t)N_NODES * 4;
    float* dinv      = (float*)(ws + off); off += (size_t)N_NODES * 4;
    int*   srcs      = (int*)(ws + off);   off += (size_t)N_EDGES * 4;        // 6.4 MB
    int*   flag      = (int*)(ws + off);

    const int*       e32 = (const int*)ei;
    const long long* e64 = (const long long*)ei;

    k_detect<<<1, 256, 0, stream>>>((const unsigned*)ei, flag);
    k_zero<<<(N_NODES + 255) / 256, 256, 0, stream>>>(cnt);
    k_gemm<<<N_NODES / 16, 256, 0, stream>>>(x, Wc, h);
    k_hist<<<(N_EDGES + 255) / 256, 256, 0, stream>>>(e32, e64, flag, cnt);
    k_scan<<<1, 1024, 0, stream>>>(cnt, row_start, cursor, dinv);
    k_fill<<<(N_EDGES + 255) / 256, 256, 0, stream>>>(e32, e64, flag, cursor, srcs);
    k_aggr<<<N_NODES / 4, 256, 0, stream>>>(h, row_start, srcs, dinv, bc, Wl, bl, out);
}

// Round 8
// 412.101 us; speedup vs baseline: 1.7307x; 1.7307x over previous
//
#include <hip/hip_runtime.h>
#include <hip/hip_bf16.h>

#define N_NODES 100000
#define N_EDGES 1600000
#define IN_DIM 128
#define HID 64
#define SCAN_BLOCKS ((N_NODES + 255) / 256)  // 391

// ---------------- threefry2x32, key = (0, 42) ----------------
__device__ __forceinline__ unsigned rotl32(unsigned x, unsigned r) {
    return (x << r) | (x >> (32u - r));
}

__device__ __forceinline__ void threefry2x32_k42(unsigned x0, unsigned x1,
                                                 unsigned& o0, unsigned& o1) {
    const unsigned ks0 = 0u;
    const unsigned ks1 = 42u;
    const unsigned ks2 = 0u ^ 42u ^ 0x1BD11BDAu;
    x0 += ks0; x1 += ks1;
    x0 += x1; x1 = rotl32(x1, 13); x1 ^= x0;
    x0 += x1; x1 = rotl32(x1, 15); x1 ^= x0;
    x0 += x1; x1 = rotl32(x1, 26); x1 ^= x0;
    x0 += x1; x1 = rotl32(x1, 6);  x1 ^= x0;
    x0 += ks1; x1 += ks2 + 1u;
    x0 += x1; x1 = rotl32(x1, 17); x1 ^= x0;
    x0 += x1; x1 = rotl32(x1, 29); x1 ^= x0;
    x0 += x1; x1 = rotl32(x1, 16); x1 ^= x0;
    x0 += x1; x1 = rotl32(x1, 24); x1 ^= x0;
    x0 += ks2; x1 += ks0 + 2u;
    x0 += x1; x1 = rotl32(x1, 13); x1 ^= x0;
    x0 += x1; x1 = rotl32(x1, 15); x1 ^= x0;
    x0 += x1; x1 = rotl32(x1, 26); x1 ^= x0;
    x0 += x1; x1 = rotl32(x1, 6);  x1 ^= x0;
    x0 += ks0; x1 += ks1 + 3u;
    x0 += x1; x1 = rotl32(x1, 17); x1 ^= x0;
    x0 += x1; x1 = rotl32(x1, 29); x1 ^= x0;
    x0 += x1; x1 = rotl32(x1, 16); x1 ^= x0;
    x0 += x1; x1 = rotl32(x1, 24); x1 ^= x0;
    x0 += ks1; x1 += ks2 + 4u;
    x0 += x1; x1 = rotl32(x1, 13); x1 ^= x0;
    x0 += x1; x1 = rotl32(x1, 15); x1 ^= x0;
    x0 += x1; x1 = rotl32(x1, 26); x1 ^= x0;
    x0 += x1; x1 = rotl32(x1, 6);  x1 ^= x0;
    x0 += ks2; x1 += ks0 + 5u;
    o0 = x0; o1 = x1;
}

// ---------------- edge-index dtype detection (int64 vs int32) ----------------
__global__ void k_detect(const unsigned* __restrict__ ei_words, int* __restrict__ flag) {
    __shared__ unsigned red[256];
    int t = threadIdx.x;
    unsigned acc = 0;
    for (int i = t; i < 4096; i += 256) acc |= ei_words[2 * i + 1];
    red[t] = acc;
    __syncthreads();
    for (int s = 128; s; s >>= 1) {
        if (t < s) red[t] |= red[t + s];
        __syncthreads();
    }
    if (t == 0) *flag = (red[0] == 0u) ? 1 : 0;  // 1 => int64
}

__device__ __forceinline__ int edge_at(const int* __restrict__ e32,
                                       const long long* __restrict__ e64,
                                       int is64, int j) {
    return is64 ? (int)e64[j] : e32[j];
}

// ---------------- h = x @ W_conv  [100000,128]x[128,64] -> fp32 ----------------
__global__ __launch_bounds__(256) void k_gemm(const float* __restrict__ x,
                                              const float* __restrict__ W,
                                              float* __restrict__ h) {
    __shared__ float Wl[IN_DIM * HID];  // 32 KB
    __shared__ float xs[16][IN_DIM];    // 8 KB
    const int t = threadIdx.x;
    const float4* W4 = (const float4*)W;
    for (int i = t; i < IN_DIM * HID / 4; i += 256) ((float4*)Wl)[i] = W4[i];
    const int base = blockIdx.x * 16;
    const float4* x4 = (const float4*)(x + (size_t)base * IN_DIM);
    for (int i = t; i < 16 * IN_DIM / 4; i += 256) ((float4*)xs)[i] = x4[i];
    __syncthreads();
    const int d = t & 63, g = t >> 6;
    float a0 = 0.f, a1 = 0.f, a2 = 0.f, a3 = 0.f;
#pragma unroll 4
    for (int k = 0; k < IN_DIM; k++) {
        float w = Wl[k * HID + d];
        a0 += xs[g][k] * w;
        a1 += xs[g + 4][k] * w;
        a2 += xs[g + 8][k] * w;
        a3 += xs[g + 12][k] * w;
    }
    h[(size_t)(base + g) * HID + d] = a0;
    h[(size_t)(base + g + 4) * HID + d] = a1;
    h[(size_t)(base + g + 8) * HID + d] = a2;
    h[(size_t)(base + g + 12) * HID + d] = a3;
}

// ---------------- CSR build ----------------
__global__ void k_zero(int* __restrict__ cnt) {
    int i = blockIdx.x * 256 + threadIdx.x;
    if (i < N_NODES) cnt[i] = 0;
}

__global__ void k_hist(const int* __restrict__ e32, const long long* __restrict__ e64,
                       const int* __restrict__ flag, int* __restrict__ cnt) {
    int e = blockIdx.x * 256 + threadIdx.x;
    if (e < N_EDGES) {
        int c = edge_at(e32, e64, *flag, N_EDGES + e);
        atomicAdd(&cnt[c], 1);
    }
}

// scan phase A: per-block sums of cnt (256 each)
__global__ __launch_bounds__(256) void k_scanA(const int* __restrict__ cnt,
                                               int* __restrict__ blocksum) {
    __shared__ int s[256];
    int t = threadIdx.x;
    int i = blockIdx.x * 256 + t;
    s[t] = (i < N_NODES) ? cnt[i] : 0;
    __syncthreads();
    for (int st = 128; st; st >>= 1) {
        if (t < st) s[t] += s[t + st];
        __syncthreads();
    }
    if (t == 0) blocksum[blockIdx.x] = s[0];
}

// scan phase B: single block exclusive scan over SCAN_BLOCKS partials
__global__ __launch_bounds__(512) void k_scanB(int* __restrict__ blocksum) {
    __shared__ int s[512];
    int t = threadIdx.x;
    s[t] = (t < SCAN_BLOCKS) ? blocksum[t] : 0;
    __syncthreads();
    for (int off = 1; off < 512; off <<= 1) {
        int v = (t >= off) ? s[t - off] : 0;
        __syncthreads();
        s[t] += v;
        __syncthreads();
    }
    if (t < SCAN_BLOCKS) blocksum[t] = s[t] - ((t < SCAN_BLOCKS) ? 0 : 0) - (t < SCAN_BLOCKS ? (t == 0 ? s[0] : s[t] - s[t - 1]) : 0) + ((t == 0) ? 0 : 0);
    // rewrite exclusive: ex[t] = inclusive[t] - orig[t]; orig = inclusive - inclusive_prev
    // simpler: ex[t] = (t==0) ? 0 : s[t-1]
    __syncthreads();
    if (t < SCAN_BLOCKS) blocksum[t] = (t == 0) ? 0 : s[t - 1];
}

// scan phase C: per-element exclusive scan within block + block offset
__global__ __launch_bounds__(256) void k_scanC(const int* __restrict__ cnt,
                                               const int* __restrict__ blocksum,
                                               int* __restrict__ row_start,
                                               int* __restrict__ cursor,
                                               float* __restrict__ dinv) {
    __shared__ int s[256];
    int t = threadIdx.x;
    int i = blockIdx.x * 256 + t;
    int my = (i < N_NODES) ? cnt[i] : 0;
    s[t] = my;
    __syncthreads();
    // Hillis-Steele inclusive scan
    for (int off = 1; off < 256; off <<= 1) {
        int v = (t >= off) ? s[t - off] : 0;
        __syncthreads();
        s[t] += v;
        __syncthreads();
    }
    if (i < N_NODES) {
        int ex = blocksum[blockIdx.x] + s[t] - my;  // exclusive prefix
        row_start[i] = ex;
        cursor[i] = ex;
        dinv[i] = rsqrtf((float)(my + 1));
        if (i == N_NODES - 1) row_start[N_NODES] = ex + my;
    }
}

__global__ void k_fill(const int* __restrict__ e32, const long long* __restrict__ e64,
                       const int* __restrict__ flag, int* __restrict__ cursor,
                       int* __restrict__ srcs) {
    int e = blockIdx.x * 256 + threadIdx.x;
    if (e >= N_EDGES) return;
    int f = *flag;
    int r = edge_at(e32, e64, f, e);
    int c = edge_at(e32, e64, f, N_EDGES + e);
    int pos = atomicAdd(&cursor[c], 1);
    srcs[pos] = r;
}

// ---------------- fused gather + self + bias/relu/dropout + [64->2] matvec ----------
__global__ __launch_bounds__(256) void k_aggr(const float* __restrict__ h,
                                              const int* __restrict__ row_start,
                                              const int* __restrict__ srcs,
                                              const float* __restrict__ dinv,
                                              const float* __restrict__ bconv,
                                              const float* __restrict__ Wlin,
                                              const float* __restrict__ blin,
                                              float* __restrict__ out) {
    const int c = blockIdx.x * 4 + (threadIdx.x >> 6);
    const int d = threadIdx.x & 63;
    const float dc = dinv[c];
    float acc = h[(size_t)c * HID + d] * dc;
    const int beg = row_start[c];
    const int end = row_start[c + 1];
    int j = beg;
    // unroll by 4 for independent outstanding loads
    for (; j + 3 < end; j += 4) {
        int r0 = srcs[j], r1 = srcs[j + 1], r2 = srcs[j + 2], r3 = srcs[j + 3];
        float w0 = dinv[r0], w1 = dinv[r1], w2 = dinv[r2], w3 = dinv[r3];
        float v0 = h[(size_t)r0 * HID + d];
        float v1 = h[(size_t)r1 * HID + d];
        float v2 = h[(size_t)r2 * HID + d];
        float v3 = h[(size_t)r3 * HID + d];
        acc += w0 * v0 + w1 * v1 + w2 * v2 + w3 * v3;
    }
    for (; j < end; j++) {
        int r = srcs[j];
        acc += dinv[r] * h[(size_t)r * HID + d];
    }
    float v = acc * dc + bconv[d];
    v = fmaxf(v, 0.f);
    unsigned i = (unsigned)(c * HID + d);
    unsigned o0, o1;
    threefry2x32_k42(0u, i, o0, o1);
    v = ((o0 ^ o1) & 0x80000000u) ? 0.f : v * 2.f;
    float a0 = v * Wlin[d * 2 + 0];
    float a1 = v * Wlin[d * 2 + 1];
#pragma unroll
    for (int off = 32; off; off >>= 1) {
        a0 += __shfl_down(a0, off);
        a1 += __shfl_down(a1, off);
    }
    if (d == 0) {
        out[(size_t)c * 2 + 0] = a0 + blin[0];
        out[(size_t)c * 2 + 1] = a1 + blin[1];
    }
}

extern "C" void kernel_launch(void* const* d_in, const int* in_sizes, int n_in,
                              void* d_out, int out_size, void* d_ws, size_t ws_size,
                              hipStream_t stream) {
    // Map inputs BY ELEMENT COUNT (all unique) — robust to positional order.
    const float* x  = (const float*)d_in[0];
    const void*  ei = d_in[1];
    const float* Wc = (const float*)d_in[2];
    const float* bc = (const float*)d_in[3];
    const float* Wl = (const float*)d_in[4];
    const float* bl = (const float*)d_in[5];
    for (int i = 0; i < n_in; i++) {
        switch (in_sizes[i]) {
            case N_NODES * IN_DIM:   x  = (const float*)d_in[i]; break;
            case 2 * N_EDGES:
            case 4 * N_EDGES:        ei = d_in[i]; break;
            case IN_DIM * HID:       Wc = (const float*)d_in[i]; break;
            case HID:                bc = (const float*)d_in[i]; break;
            case HID * 2:            Wl = (const float*)d_in[i]; break;
            case 2:                  bl = (const float*)d_in[i]; break;
            default: break;
        }
    }
    float* out = (float*)d_out;

    char* ws = (char*)d_ws;
    size_t off = 0;
    float* h         = (float*)(ws + off); off += (size_t)N_NODES * HID * 4;  // 25.6 MB
    int*   cnt       = (int*)(ws + off);   off += (size_t)N_NODES * 4;
    int*   row_start = (int*)(ws + off);   off += (size_t)(N_NODES + 4) * 4;
    int*   cursor    = (int*)(ws + off);   off += (size_t)N_NODES * 4;
    float* dinv      = (float*)(ws + off); off += (size_t)N_NODES * 4;
    int*   srcs      = (int*)(ws + off);   off += (size_t)N_EDGES * 4;        // 6.4 MB
    int*   blocksum  = (int*)(ws + off);   off += (size_t)(SCAN_BLOCKS + 4) * 4;
    int*   flag      = (int*)(ws + off);

    const int*       e32 = (const int*)ei;
    const long long* e64 = (const long long*)ei;

    k_detect<<<1, 256, 0, stream>>>((const unsigned*)ei, flag);
    k_zero<<<(N_NODES + 255) / 256, 256, 0, stream>>>(cnt);
    k_gemm<<<N_NODES / 16, 256, 0, stream>>>(x, Wc, h);
    k_hist<<<(N_EDGES + 255) / 256, 256, 0, stream>>>(e32, e64, flag, cnt);
    k_scanA<<<SCAN_BLOCKS, 256, 0, stream>>>(cnt, blocksum);
    k_scanB<<<1, 512, 0, stream>>>(blocksum);
    k_scanC<<<SCAN_BLOCKS, 256, 0, stream>>>(cnt, blocksum, row_start, cursor, dinv);
    k_fill<<<(N_EDGES + 255) / 256, 256, 0, stream>>>(e32, e64, flag, cursor, srcs);
    k_aggr<<<N_NODES / 4, 256, 0, stream>>>(h, row_start, srcs, dinv, bc, Wl, bl, out);
}